// Round 1
// baseline (1976.410 us; speedup 1.0000x reference)
//
#include <hip/hip_runtime.h>
#include <cmath>

typedef _Float16 f16;
typedef _Float16 f16x8 __attribute__((ext_vector_type(8)));
typedef _Float16 f16x4 __attribute__((ext_vector_type(4)));
typedef float f32x4 __attribute__((ext_vector_type(4)));

#define EPSF 1e-6f

// ---------------- async global->LDS, 16B per lane ----------------
__device__ __forceinline__ void gload16(const f16* g, f16* l) {
  __builtin_amdgcn_global_load_lds(
      (__attribute__((address_space(1))) void*)g,
      (__attribute__((address_space(3))) void*)l, 16, 0, 0);
}

// ---------------- weight transpose fp32[K,N] -> f16[N,K] ----------------
__global__ void wtr_k(const float* __restrict__ W, f16* __restrict__ WT, int K, int N) {
  __shared__ float t[32][33];
  const int nb = blockIdx.x * 32, kb = blockIdx.y * 32;
  const int tx = threadIdx.x, ty = threadIdx.y;
#pragma unroll
  for (int i = ty; i < 32; i += 8) t[i][tx] = W[(size_t)(kb + i) * N + nb + tx];
  __syncthreads();
#pragma unroll
  for (int i = ty; i < 32; i += 8) WT[(size_t)(nb + i) * K + kb + tx] = (f16)t[tx][i];
}

// ---------------- per-(b,sblk,d) partial sum of clipped x^2 ----------------
__global__ void colsq_k(const float* __restrict__ x, float* __restrict__ part) {
  const int d = blockIdx.x * 256 + threadIdx.x;
  const int sb = blockIdx.y;
  const int b = blockIdx.z;
  const float* p = x + ((size_t)b * 4096 + (size_t)sb * 256) * 1024 + d;
  float acc = 0.f;
#pragma unroll 4
  for (int s = 0; s < 256; ++s) {
    float v = p[(size_t)s * 1024];
    v = fminf(fmaxf(v, -10.f), 10.f);
    acc = fmaf(v, v, acc);
  }
  part[((size_t)b * 16 + sb) * 1024 + d] = acc;
}

// ---------------- Gs, Gt -> Gsum, amp per (b,d) ----------------
__global__ void stats_k(const float* __restrict__ part, float* __restrict__ Gsum,
                        float* __restrict__ amp) {
  const int b = blockIdx.x;
  const int t = threadIdx.x;
  __shared__ double red[256];
  float cs[4];
  double tot = 0.0;
#pragma unroll
  for (int i = 0; i < 4; ++i) {
    const int d = t + i * 256;
    double s = 0.0;
    for (int k = 0; k < 16; ++k) s += (double)part[((size_t)b * 16 + k) * 1024 + d];
    cs[i] = (float)s;
    tot += s;
  }
  red[t] = tot;
  __syncthreads();
  for (int st = 128; st > 0; st >>= 1) {
    if (t < st) red[t] += red[t + st];
    __syncthreads();
  }
  const float Gs = fmaxf(sqrtf((float)red[0] + EPSF), EPSF);
#pragma unroll
  for (int i = 0; i < 4; ++i) {
    const int d = t + i * 256;
    const float Gt = fmaxf(sqrtf(cs[i] + EPSF), EPSF);
    const float gs = Gs + Gt;
    Gsum[(b << 10) + d] = gs;
    amp[(b << 10) + d] = sqrtf(gs * gs + EPSF);
  }
}

// ---------------- rowterm[b,d] = amp[b,:]@Wa[:,d] + ba + bp + gate_bias ----------------
__global__ void rowterm_k(const float* __restrict__ amp, const float* __restrict__ Wa,
                          const float* __restrict__ ba, const float* __restrict__ bp,
                          const float* __restrict__ gbias, float* __restrict__ rt) {
  const int b = blockIdx.y;
  const int d = blockIdx.x * 256 + threadIdx.x;
  const float* a = amp + (b << 10);
  double acc = 0.0;
  for (int k = 0; k < 1024; ++k) acc += (double)a[k] * (double)Wa[((size_t)k << 10) + d];
  rt[(b << 10) + d] = (float)acc + ba[d] + bp[d] + gbias[d];
}

// ---------------- ph materialization: two-valued by sign(x) ----------------
__global__ void ph_k(const float* __restrict__ x, f16* __restrict__ ph, float phPos,
                     float phNeg) {
  const size_t i = (size_t)blockIdx.x * 256 + threadIdx.x;
  const float4 v = ((const float4*)x)[i];
  f16x4 o;
  o[0] = (f16)(v.x < 0.f ? phNeg : phPos);
  o[1] = (f16)(v.y < 0.f ? phNeg : phPos);
  o[2] = (f16)(v.z < 0.f ? phNeg : phPos);
  o[3] = (f16)(v.w < 0.f ? phNeg : phPos);
  ((f16x4*)ph)[i] = o;
}

// ---------------- RMSNorm row kernel: f32 in -> f16 out ----------------
__global__ void rms_k(const float* __restrict__ wave, const float* __restrict__ g,
                      f16* __restrict__ o) {
  const size_t row = blockIdx.x;
  const int t = threadIdx.x;
  const float4 v = ((const float4*)(wave + row * 1024))[t];
  float ss = v.x * v.x + v.y * v.y + v.z * v.z + v.w * v.w;
#pragma unroll
  for (int s = 32; s > 0; s >>= 1) ss += __shfl_down(ss, s);
  __shared__ float red[4];
  if ((t & 63) == 0) red[t >> 6] = ss;
  __syncthreads();
  const float tot = red[0] + red[1] + red[2] + red[3];
  const float r = rsqrtf(tot * (1.f / 1024.f) + EPSF);
  const float4 gv = ((const float4*)g)[t];
  f16x4 ov;
  ov[0] = (f16)(v.x * r * gv.x);
  ov[1] = (f16)(v.y * r * gv.y);
  ov[2] = (f16)(v.z * r * gv.z);
  ov[3] = (f16)(v.w * r * gv.w);
  ((f16x4*)(o + row * 1024))[t] = ov;
}

// ---------------- MFMA GEMM: C[R,N] = A[R,K] * BT[N,K]^T, epilogue fused ----------------
// EPI: 0 = +bias -> f32 ; 1 = accumulate into f32 ; 2 = +bias -> f16 ;
//      3 = gelu(+bias) -> f16 ; 4 = gate epilogue (sigmoid, cr/ci split -> gr,gi f16)
template <int EPI>
__global__ __launch_bounds__(256) void gemm_k(
    const f16* __restrict__ A, int lda, const f16* __restrict__ BT, int ldb, int K,
    const float* __restrict__ bias, float* __restrict__ outF, f16* __restrict__ outH,
    int ldo, const f16* __restrict__ phm, const float* __restrict__ rowterm,
    const float* __restrict__ Gsum, f16* __restrict__ gr, f16* __restrict__ gi, int r0,
    float ratioNeg, float stNeg) {
  __shared__ f16 As[2][4096];  // 128 rows x 32 k
  __shared__ f16 Bs[2][4096];
  const int tid = threadIdx.x;
  const int wv = tid >> 6, ln = tid & 63;
  const size_t rbase = (size_t)blockIdx.x * 128;
  const size_t cbase = (size_t)blockIdx.y * 128;

  // staging: slot s = wv*64+ln covers tile row s>>2, k-part (s&3)*8 (16B per lane)
  const int srow = (wv << 4) + (ln >> 2);
  const int skel = (ln & 3) << 3;
  const f16* gA = A + (rbase + srow) * (size_t)lda + skel;
  const f16* gB = BT + (cbase + srow) * (size_t)ldb + skel;

  f32x4 acc[4][4];
  const f32x4 zero = {0.f, 0.f, 0.f, 0.f};
#pragma unroll
  for (int m = 0; m < 4; ++m)
#pragma unroll
    for (int n = 0; n < 4; ++n) acc[m][n] = zero;

  const int nk = K >> 5;
  {
    f16* la = &As[0][wv << 9];
    f16* lb = &Bs[0][wv << 9];
    gload16(gA, la);
    gload16(gA + (size_t)64 * lda, la + 2048);
    gload16(gB, lb);
    gload16(gB + (size_t)64 * ldb, lb + 2048);
  }
  __syncthreads();

  const int arow = ln & 15;
  const int kg = (ln >> 4) << 3;
  const int wr = (wv >> 1) << 6;
  const int wc = (wv & 1) << 6;

  for (int t = 0; t < nk; ++t) {
    const int cur = t & 1;
    if (t + 1 < nk) {
      const size_t ko = (size_t)(t + 1) << 5;
      f16* la = &As[cur ^ 1][wv << 9];
      f16* lb = &Bs[cur ^ 1][wv << 9];
      gload16(gA + ko, la);
      gload16(gA + ko + (size_t)64 * lda, la + 2048);
      gload16(gB + ko, lb);
      gload16(gB + ko + (size_t)64 * ldb, lb + 2048);
    }
    const f16* ap = &As[cur][(wr + arow) * 32 + kg];
    const f16* bp = &Bs[cur][(wc + arow) * 32 + kg];
    f16x8 af[4], bfr[4];
#pragma unroll
    for (int m = 0; m < 4; ++m) af[m] = *(const f16x8*)(ap + m * 512);
#pragma unroll
    for (int n = 0; n < 4; ++n) bfr[n] = *(const f16x8*)(bp + n * 512);
#pragma unroll
    for (int m = 0; m < 4; ++m)
#pragma unroll
      for (int n = 0; n < 4; ++n)
        acc[m][n] = __builtin_amdgcn_mfma_f32_16x16x32_f16(af[m], bfr[n], acc[m][n], 0, 0, 0);
    __syncthreads();
  }

  // epilogue; C/D layout: col = lane&15, row = (lane>>4)*4 + j
  const int r4 = (ln >> 4) << 2;
  const int c0 = ln & 15;
#pragma unroll
  for (int m = 0; m < 4; ++m) {
#pragma unroll
    for (int n = 0; n < 4; ++n) {
      const size_t col = cbase + wc + n * 16 + c0;
#pragma unroll
      for (int j = 0; j < 4; ++j) {
        const size_t row = rbase + wr + m * 16 + r4 + j;
        const float v = acc[m][n][j];
        if constexpr (EPI == 0) {
          outF[row * (size_t)ldo + col] = v + bias[col];
        } else if constexpr (EPI == 1) {
          outF[row * (size_t)ldo + col] += v;
        } else if constexpr (EPI == 2) {
          outH[row * (size_t)ldo + col] = (f16)(v + bias[col]);
        } else if constexpr (EPI == 3) {
          const float u = v + bias[col];
          outH[row * (size_t)ldo + col] = (f16)(0.5f * u * (1.f + erff(u * 0.70710678118654752f)));
        } else {
          const int gb = (int)(((size_t)r0 + row) >> 12);  // S = 4096
          const float pre = v + rowterm[((size_t)gb << 10) + col];
          const float gate = 1.f / (1.f + expf(-pre));
          const float ph = (float)phm[row * 1024 + col];
          const bool neg = ph > 2.f;
          const float gs = Gsum[((size_t)gb << 10) + col];
          const float cr = neg ? gs * ratioNeg : 0.f;
          const float ci = gs * (neg ? stNeg : 1.f);
          gr[row * 1024 + col] = (f16)(cr * gate);
          gi[row * 1024 + col] = (f16)(ci * gate);
        }
      }
    }
  }
}

extern "C" void kernel_launch(void* const* d_in, const int* in_sizes, int n_in,
                              void* d_out, int out_size, void* d_ws, size_t ws_size,
                              hipStream_t stream) {
  const float* x     = (const float*)d_in[0];
  const float* Wa    = (const float*)d_in[1];
  const float* ba    = (const float*)d_in[2];
  const float* Wp    = (const float*)d_in[3];
  const float* bp    = (const float*)d_in[4];
  const float* gbias = (const float*)d_in[5];
  const float* w1r   = (const float*)d_in[6];
  const float* b1r   = (const float*)d_in[7];
  const float* w2r   = (const float*)d_in[8];
  const float* b2r   = (const float*)d_in[9];
  const float* w1i   = (const float*)d_in[10];
  const float* b1i   = (const float*)d_in[11];
  const float* w2i   = (const float*)d_in[12];
  const float* b2i   = (const float*)d_in[13];
  const float* We    = (const float*)d_in[14];
  const float* be    = (const float*)d_in[15];
  const float* grms  = (const float*)d_in[16];
  const float* wf1   = (const float*)d_in[17];
  const float* bf1   = (const float*)d_in[18];
  const float* wf2   = (const float*)d_in[19];
  const float* bf2   = (const float*)d_in[20];
  float* out = (float*)d_out;

  char* ws = (char*)d_ws;
  size_t off = 0;
  auto alloc = [&](size_t bytes) -> void* {
    void* p = (void*)(ws + off);
    off += (bytes + 255) & ~(size_t)255;
    return p;
  };

  f16* WpT   = (f16*)alloc((size_t)1024 * 1024 * 2);
  f16* w1rT  = (f16*)alloc((size_t)4096 * 1024 * 2);
  f16* w2rT  = (f16*)alloc((size_t)1024 * 4096 * 2);
  f16* w1iT  = (f16*)alloc((size_t)4096 * 1024 * 2);
  f16* w2iT  = (f16*)alloc((size_t)1024 * 4096 * 2);
  f16* WeT   = (f16*)alloc((size_t)1024 * 2048 * 2);
  f16* wf1T  = (f16*)alloc((size_t)2048 * 1024 * 2);
  f16* wf2T  = (f16*)alloc((size_t)1024 * 2048 * 2);
  float* part    = (float*)alloc((size_t)4 * 16 * 1024 * 4);
  float* GsumB   = (float*)alloc((size_t)4 * 1024 * 4);
  float* ampB    = (float*)alloc((size_t)4 * 1024 * 4);
  float* rowterm = (float*)alloc((size_t)4 * 1024 * 4);

  {  // weight transposes + f16 casts (grid = (N/32, K/32) for W[K,N])
    dim3 b(32, 8);
    wtr_k<<<dim3(32, 32), b, 0, stream>>>(Wp, WpT, 1024, 1024);
    wtr_k<<<dim3(128, 32), b, 0, stream>>>(w1r, w1rT, 1024, 4096);
    wtr_k<<<dim3(32, 128), b, 0, stream>>>(w2r, w2rT, 4096, 1024);
    wtr_k<<<dim3(128, 32), b, 0, stream>>>(w1i, w1iT, 1024, 4096);
    wtr_k<<<dim3(32, 128), b, 0, stream>>>(w2i, w2iT, 4096, 1024);
    wtr_k<<<dim3(32, 64), b, 0, stream>>>(We, WeT, 2048, 1024);
    wtr_k<<<dim3(64, 32), b, 0, stream>>>(wf1, wf1T, 1024, 2048);
    wtr_k<<<dim3(32, 64), b, 0, stream>>>(wf2, wf2T, 2048, 1024);
  }

  colsq_k<<<dim3(4, 16, 4), 256, 0, stream>>>(x, part);
  stats_k<<<4, 256, 0, stream>>>(part, GsumB, ampB);
  rowterm_k<<<dim3(4, 4), 256, 0, stream>>>(ampB, Wa, ba, bp, gbias, rowterm);

  // wave_repr collapses: ratio = (x<0 ? -0.99 : 0), sqrt_term = (x<0 ? sqrt(1-.99^2) : 1)
  const float ratioNeg = -0.99f;
  const float stNeg = sqrtf(fmaxf(1.0f - 0.99f * 0.99f, EPSF));
  const float phPos = atan2f(1.0f, 0.0f);
  const float phNeg = atan2f(stNeg, ratioNeg);

  const long Ntok = (long)in_sizes[0] / 1024;  // 16384
  const size_t staticEnd = off;
  const size_t perRow = 14336;  // 3 x 2KB f16 bufs + 8KB big region per row
  long R = (long)((ws_size > staticEnd ? ws_size - staticEnd : 0) / perRow);
  R &= ~127L;
  if (R > Ntok) R = Ntok;
  if (R < 128) R = 128;

  char* cb = ws + staticEnd;
  f16* phB = (f16*)cb;                          // R x 1024
  f16* grB = (f16*)(cb + (size_t)R * 2048);     // R x 1024
  f16* giB = (f16*)(cb + (size_t)R * 4096);     // R x 1024
  char* big = cb + (size_t)R * 6144;            // R x 8192 bytes
  f16* h1B = (f16*)big;                         // R x 4096 f16
  float* waveF = (float*)big;                   // R x 1024 f32 (first half, after h1 dead)
  f16* h2B = (f16*)(big + (size_t)R * 4096);    // R x 2048 f16 (second half)
  f16* rpB = phB;                               // reuse after GEMM1 consumed ph
  f16* ipB = grB;                               // reuse after GEMM2 consumed gr
  f16* outB = giB;                              // reuse after GEMM4 consumed gi

  for (long r0 = 0; r0 < Ntok; r0 += R) {
    const long Rc = (Ntok - r0 < R) ? (Ntok - r0) : R;
    const int gx = (int)(Rc / 128);
    ph_k<<<dim3((int)Rc), 256, 0, stream>>>(x + r0 * 1024, phB, phPos, phNeg);
    // gate: pre = ph@Wp + rowterm; gr/gi = (cr/ci)*sigmoid(pre)
    gemm_k<4><<<dim3(gx, 8), 256, 0, stream>>>(phB, 1024, WpT, 1024, 1024, nullptr,
        nullptr, nullptr, 1024, phB, rowterm, GsumB, grB, giB, (int)r0, ratioNeg, stNeg);
    // real-channel FFN
    gemm_k<3><<<dim3(gx, 32), 256, 0, stream>>>(grB, 1024, w1rT, 1024, 1024, b1r,
        nullptr, h1B, 4096, nullptr, nullptr, nullptr, nullptr, nullptr, 0, 0.f, 0.f);
    gemm_k<2><<<dim3(gx, 8), 256, 0, stream>>>(h1B, 4096, w2rT, 4096, 4096, b2r,
        nullptr, rpB, 1024, nullptr, nullptr, nullptr, nullptr, nullptr, 0, 0.f, 0.f);
    // imag-channel FFN
    gemm_k<3><<<dim3(gx, 32), 256, 0, stream>>>(giB, 1024, w1iT, 1024, 1024, b1i,
        nullptr, h1B, 4096, nullptr, nullptr, nullptr, nullptr, nullptr, 0, 0.f, 0.f);
    gemm_k<2><<<dim3(gx, 8), 256, 0, stream>>>(h1B, 4096, w2iT, 4096, 4096, b2i,
        nullptr, ipB, 1024, nullptr, nullptr, nullptr, nullptr, nullptr, 0, 0.f, 0.f);
    // wave = rp@We_top + ip@We_bot + be
    gemm_k<0><<<dim3(gx, 8), 256, 0, stream>>>(rpB, 1024, WeT, 2048, 1024, be,
        waveF, nullptr, 1024, nullptr, nullptr, nullptr, nullptr, nullptr, 0, 0.f, 0.f);
    gemm_k<1><<<dim3(gx, 8), 256, 0, stream>>>(ipB, 1024, WeT + 1024, 2048, 1024, nullptr,
        waveF, nullptr, 1024, nullptr, nullptr, nullptr, nullptr, nullptr, 0, 0.f, 0.f);
    rms_k<<<dim3((int)Rc), 256, 0, stream>>>(waveF, grms, outB);
    // block FFN
    gemm_k<3><<<dim3(gx, 16), 256, 0, stream>>>(outB, 1024, wf1T, 1024, 1024, bf1,
        nullptr, h2B, 2048, nullptr, nullptr, nullptr, nullptr, nullptr, 0, 0.f, 0.f);
    gemm_k<0><<<dim3(gx, 8), 256, 0, stream>>>(h2B, 2048, wf2T, 2048, 2048, bf2,
        out + r0 * 1024, nullptr, 1024, nullptr, nullptr, nullptr, nullptr, nullptr, 0, 0.f, 0.f);
  }
}

// Round 2
// 1654.468 us; speedup vs baseline: 1.1946x; 1.1946x over previous
//
#include <hip/hip_runtime.h>
#include <cmath>

typedef _Float16 f16;
typedef _Float16 f16x8 __attribute__((ext_vector_type(8)));
typedef _Float16 f16x4 __attribute__((ext_vector_type(4)));
typedef float f32x4 __attribute__((ext_vector_type(4)));

#define EPSF 1e-6f

// ---------------- async global->LDS, 16B per lane ----------------
__device__ __forceinline__ void gload16(const f16* g, f16* l) {
  __builtin_amdgcn_global_load_lds(
      (__attribute__((address_space(1))) void*)g,
      (__attribute__((address_space(3))) void*)l, 16, 0, 0);
}

// ---------------- weight transpose fp32[K,N] -> f16[N,K] ----------------
__global__ void wtr_k(const float* __restrict__ W, f16* __restrict__ WT, int K, int N) {
  __shared__ float t[32][33];
  const int nb = blockIdx.x * 32, kb = blockIdx.y * 32;
  const int tx = threadIdx.x, ty = threadIdx.y;
#pragma unroll
  for (int i = ty; i < 32; i += 8) t[i][tx] = W[(size_t)(kb + i) * N + nb + tx];
  __syncthreads();
#pragma unroll
  for (int i = ty; i < 32; i += 8) WT[(size_t)(nb + i) * K + kb + tx] = (f16)t[tx][i];
}

// ---------------- flat fp32 -> f16 cast ----------------
__global__ void cast_k(const float* __restrict__ W, f16* __restrict__ H) {
  const size_t i = (size_t)blockIdx.x * 256 + threadIdx.x;
  const float4 v = ((const float4*)W)[i];
  f16x4 o;
  o[0] = (f16)v.x; o[1] = (f16)v.y; o[2] = (f16)v.z; o[3] = (f16)v.w;
  ((f16x4*)H)[i] = o;
}

// ---------------- per-(b,sblk,d) partial sum of clipped x^2 ----------------
__global__ void colsq_k(const float* __restrict__ x, float* __restrict__ part) {
  const int d = blockIdx.x * 256 + threadIdx.x;
  const int sb = blockIdx.y;
  const int b = blockIdx.z;
  const float* p = x + ((size_t)b * 4096 + (size_t)sb * 256) * 1024 + d;
  float acc = 0.f;
#pragma unroll 4
  for (int s = 0; s < 256; ++s) {
    float v = p[(size_t)s * 1024];
    v = fminf(fmaxf(v, -10.f), 10.f);
    acc = fmaf(v, v, acc);
  }
  part[((size_t)b * 16 + sb) * 1024 + d] = acc;
}

// ---------------- Gs, Gt -> Gsum, amp per (b,d) ----------------
__global__ void stats_k(const float* __restrict__ part, float* __restrict__ Gsum,
                        float* __restrict__ amp) {
  const int b = blockIdx.x;
  const int t = threadIdx.x;
  __shared__ double red[256];
  float cs[4];
  double tot = 0.0;
#pragma unroll
  for (int i = 0; i < 4; ++i) {
    const int d = t + i * 256;
    double s = 0.0;
    for (int k = 0; k < 16; ++k) s += (double)part[((size_t)b * 16 + k) * 1024 + d];
    cs[i] = (float)s;
    tot += s;
  }
  red[t] = tot;
  __syncthreads();
  for (int st = 128; st > 0; st >>= 1) {
    if (t < st) red[t] += red[t + st];
    __syncthreads();
  }
  const float Gs = fmaxf(sqrtf((float)red[0] + EPSF), EPSF);
#pragma unroll
  for (int i = 0; i < 4; ++i) {
    const int d = t + i * 256;
    const float Gt = fmaxf(sqrtf(cs[i] + EPSF), EPSF);
    const float gs = Gs + Gt;
    Gsum[(b << 10) + d] = gs;
    amp[(b << 10) + d] = sqrtf(gs * gs + EPSF);
  }
}

// ---------------- rowterm[b,d] = amp[b,:]@Wa[:,d] + ba + bp + gate_bias ----------------
__global__ void rowterm_k(const float* __restrict__ amp, const float* __restrict__ Wa,
                          const float* __restrict__ ba, const float* __restrict__ bp,
                          const float* __restrict__ gbias, float* __restrict__ rt) {
  const int b = blockIdx.y;
  const int d = blockIdx.x * 256 + threadIdx.x;
  const float* a = amp + (b << 10);
  double acc = 0.0;
  for (int k = 0; k < 1024; ++k) acc += (double)a[k] * (double)Wa[((size_t)k << 10) + d];
  rt[(b << 10) + d] = (float)acc + ba[d] + bp[d] + gbias[d];
}

// ---------------- combined bias: bc = b2r@We_top + b2i@We_bot + be ----------------
__global__ void bc_k(const float* __restrict__ b2r, const float* __restrict__ b2i,
                     const float* __restrict__ We, const float* __restrict__ be,
                     float* __restrict__ bc) {
  const int n = blockIdx.x * 256 + threadIdx.x;
  double a = 0.0;
  for (int j = 0; j < 1024; ++j) a += (double)b2r[j] * (double)We[(size_t)j * 1024 + n];
  for (int j = 0; j < 1024; ++j)
    a += (double)b2i[j] * (double)We[(size_t)(1024 + j) * 1024 + n];
  bc[n] = (float)a + be[n];
}

// ---------------- ph materialization: two-valued by sign(x) ----------------
__global__ void ph_k(const float* __restrict__ x, f16* __restrict__ ph, float phPos,
                     float phNeg) {
  const size_t i = (size_t)blockIdx.x * 256 + threadIdx.x;
  const float4 v = ((const float4*)x)[i];
  f16x4 o;
  o[0] = (f16)(v.x < 0.f ? phNeg : phPos);
  o[1] = (f16)(v.y < 0.f ? phNeg : phPos);
  o[2] = (f16)(v.z < 0.f ? phNeg : phPos);
  o[3] = (f16)(v.w < 0.f ? phNeg : phPos);
  ((f16x4*)ph)[i] = o;
}

// ---------------- RMSNorm row kernel: f32 in -> f16 out ----------------
__global__ void rms_k(const float* __restrict__ wave, const float* __restrict__ g,
                      f16* __restrict__ o) {
  const size_t row = blockIdx.x;
  const int t = threadIdx.x;
  const float4 v = ((const float4*)(wave + row * 1024))[t];
  float ss = v.x * v.x + v.y * v.y + v.z * v.z + v.w * v.w;
#pragma unroll
  for (int s = 32; s > 0; s >>= 1) ss += __shfl_down(ss, s);
  __shared__ float red[4];
  if ((t & 63) == 0) red[t >> 6] = ss;
  __syncthreads();
  const float tot = red[0] + red[1] + red[2] + red[3];
  const float r = rsqrtf(tot * (1.f / 1024.f) + EPSF);
  const float4 gv = ((const float4*)g)[t];
  f16x4 ov;
  ov[0] = (f16)(v.x * r * gv.x);
  ov[1] = (f16)(v.y * r * gv.y);
  ov[2] = (f16)(v.z * r * gv.z);
  ov[3] = (f16)(v.w * r * gv.w);
  ((f16x4*)(o + row * 1024))[t] = ov;
}

// ---------------- MFMA GEMM: C[R,N] = A[R,K] * BT[N,K]^T, epilogue fused ----------------
// EPI: 0 = +bias -> f32 ; 3 = gelu(+bias) -> f16 ; 4 = gate epilogue -> gr,gi f16 ;
//      5 = plain -> f16 (no bias)
template <int EPI>
__global__ __launch_bounds__(256) void gemm_k(
    const f16* __restrict__ A, int lda, const f16* __restrict__ BT, int ldb, int K,
    const float* __restrict__ bias, float* __restrict__ outF, f16* __restrict__ outH,
    int ldo, const f16* __restrict__ phm, const float* __restrict__ rowterm,
    const float* __restrict__ Gsum, f16* __restrict__ gr, f16* __restrict__ gi, int r0,
    float ratioNeg, float stNeg) {
  __shared__ f16 As[2][4096];  // 128 rows x 32 k (k-slots XOR-swizzled by row)
  __shared__ f16 Bs[2][4096];
  const int tid = threadIdx.x;
  const int wv = tid >> 6, ln = tid & 63;

  // bijective XCD-aware swizzle (m204): each XCD gets a contiguous run of tiles
  const int gxd = gridDim.x;
  const int bid = blockIdx.y * gxd + blockIdx.x;
  const int nwg = gxd * gridDim.y;
  const int q = nwg >> 3, rr = nwg & 7;
  const int xcd = bid & 7, idx = bid >> 3;
  const int swz = (xcd < rr ? xcd * (q + 1) : rr * (q + 1) + (xcd - rr) * q) + idx;
  const int bx = swz % gxd, by = swz / gxd;

  const size_t rbase = (size_t)bx * 128;
  const size_t cbase = (size_t)by * 128;

  // staging: slot s = wv*64+ln covers tile row s>>2; global k-slot pre-swizzled so
  // LDS stays linear but holds data for slot (ln&3)^((row>>1)&3)  [rule 21]
  const int srow = (wv << 4) + (ln >> 2);
  const int ksw = (((ln & 3) ^ ((srow >> 1) & 3)) << 3);
  const f16* gA = A + (rbase + srow) * (size_t)lda + ksw;
  const f16* gB = BT + (cbase + srow) * (size_t)ldb + ksw;

  f32x4 acc[4][4];
  const f32x4 zero = {0.f, 0.f, 0.f, 0.f};
#pragma unroll
  for (int m = 0; m < 4; ++m)
#pragma unroll
    for (int n = 0; n < 4; ++n) acc[m][n] = zero;

  const int nk = K >> 5;
  {
    f16* la = &As[0][wv << 9];
    f16* lb = &Bs[0][wv << 9];
    gload16(gA, la);
    gload16(gA + (size_t)64 * lda, la + 2048);
    gload16(gB, lb);
    gload16(gB + (size_t)64 * ldb, lb + 2048);
  }
  __syncthreads();

  const int arow = ln & 15;
  // read-side XOR matches the staged permutation: data for k-group (ln>>4) of row r
  // lives at LDS slot (ln>>4)^((r>>1)&3); r bits 1..2 == arow bits 1..2 for all m
  const int kg = (((ln >> 4) ^ ((arow >> 1) & 3)) << 3);
  const int wr = (wv >> 1) << 6;
  const int wc = (wv & 1) << 6;

  for (int t = 0; t < nk; ++t) {
    const int cur = t & 1;
    if (t + 1 < nk) {
      const size_t ko = (size_t)(t + 1) << 5;
      f16* la = &As[cur ^ 1][wv << 9];
      f16* lb = &Bs[cur ^ 1][wv << 9];
      gload16(gA + ko, la);
      gload16(gA + ko + (size_t)64 * lda, la + 2048);
      gload16(gB + ko, lb);
      gload16(gB + ko + (size_t)64 * ldb, lb + 2048);
    }
    const f16* ap = &As[cur][(wr + arow) * 32 + kg];
    const f16* bp = &Bs[cur][(wc + arow) * 32 + kg];
    f16x8 af[4], bfr[4];
#pragma unroll
    for (int m = 0; m < 4; ++m) af[m] = *(const f16x8*)(ap + m * 512);
#pragma unroll
    for (int n = 0; n < 4; ++n) bfr[n] = *(const f16x8*)(bp + n * 512);
#pragma unroll
    for (int m = 0; m < 4; ++m)
#pragma unroll
      for (int n = 0; n < 4; ++n)
        acc[m][n] = __builtin_amdgcn_mfma_f32_16x16x32_f16(af[m], bfr[n], acc[m][n], 0, 0, 0);
    __syncthreads();
  }

  // epilogue; C/D layout: col = lane&15, row = (lane>>4)*4 + j
  const int r4 = (ln >> 4) << 2;
  const int c0 = ln & 15;
#pragma unroll
  for (int m = 0; m < 4; ++m) {
#pragma unroll
    for (int n = 0; n < 4; ++n) {
      const size_t col = cbase + wc + n * 16 + c0;
#pragma unroll
      for (int j = 0; j < 4; ++j) {
        const size_t row = rbase + wr + m * 16 + r4 + j;
        const float v = acc[m][n][j];
        if constexpr (EPI == 0) {
          outF[row * (size_t)ldo + col] = v + bias[col];
        } else if constexpr (EPI == 3) {
          const float u = v + bias[col];
          outH[row * (size_t)ldo + col] = (f16)(0.5f * u * (1.f + erff(u * 0.70710678118654752f)));
        } else if constexpr (EPI == 4) {
          const int gb = (int)(((size_t)r0 + row) >> 12);  // S = 4096
          const float pre = v + rowterm[((size_t)gb << 10) + col];
          const float gate = 1.f / (1.f + expf(-pre));
          const float ph = (float)phm[row * 1024 + col];
          const bool neg = ph > 2.f;
          const float gs = Gsum[((size_t)gb << 10) + col];
          const float cr = neg ? gs * ratioNeg : 0.f;
          const float ci = gs * (neg ? stNeg : 1.f);
          gr[row * 1024 + col] = (f16)(cr * gate);
          gi[row * 1024 + col] = (f16)(ci * gate);
        } else {  // EPI == 5
          outH[row * (size_t)ldo + col] = (f16)v;
        }
      }
    }
  }
}

extern "C" void kernel_launch(void* const* d_in, const int* in_sizes, int n_in,
                              void* d_out, int out_size, void* d_ws, size_t ws_size,
                              hipStream_t stream) {
  const float* x     = (const float*)d_in[0];
  const float* Wa    = (const float*)d_in[1];
  const float* ba    = (const float*)d_in[2];
  const float* Wp    = (const float*)d_in[3];
  const float* bp    = (const float*)d_in[4];
  const float* gbias = (const float*)d_in[5];
  const float* w1r   = (const float*)d_in[6];
  const float* b1r   = (const float*)d_in[7];
  const float* w2r   = (const float*)d_in[8];
  const float* b2r   = (const float*)d_in[9];
  const float* w1i   = (const float*)d_in[10];
  const float* b1i   = (const float*)d_in[11];
  const float* w2i   = (const float*)d_in[12];
  const float* b2i   = (const float*)d_in[13];
  const float* We    = (const float*)d_in[14];
  const float* be    = (const float*)d_in[15];
  const float* grms  = (const float*)d_in[16];
  const float* wf1   = (const float*)d_in[17];
  const float* bf1   = (const float*)d_in[18];
  const float* wf2   = (const float*)d_in[19];
  const float* bf2   = (const float*)d_in[20];
  float* out = (float*)d_out;

  char* ws = (char*)d_ws;
  size_t off = 0;
  auto alloc = [&](size_t bytes) -> void* {
    void* p = (void*)(ws + off);
    off += (bytes + 255) & ~(size_t)255;
    return p;
  };

  // persistent across the whole launch
  f16* WpT   = (f16*)alloc((size_t)1024 * 1024 * 2);
  f16* w1rT  = (f16*)alloc((size_t)4096 * 1024 * 2);
  f16* w1iT  = (f16*)alloc((size_t)4096 * 1024 * 2);
  f16* wf1T  = (f16*)alloc((size_t)2048 * 1024 * 2);
  f16* wf2T  = (f16*)alloc((size_t)1024 * 2048 * 2);
  f16* WcT   = (f16*)alloc((size_t)1024 * 8192 * 2);  // [n][k] fused w2@We
  float* part    = (float*)alloc((size_t)4 * 16 * 1024 * 4);
  float* GsumB   = (float*)alloc((size_t)4 * 1024 * 4);
  float* ampB    = (float*)alloc((size_t)4 * 1024 * 4);
  float* rowterm = (float*)alloc((size_t)4 * 1024 * 4);
  float* bcB     = (float*)alloc((size_t)1024 * 4);
  const size_t staticEnd = off;

  // temporaries for the Wc precompute, overlapping the chunk region (dead before
  // any chunk kernel writes there; stream ordering guarantees sequencing)
  char* tmp = ws + staticEnd;
  f16* WeT  = (f16*)tmp;                                   // [1024][2048], 4 MB
  f16* w2rH = (f16*)(tmp + (size_t)4 * 1024 * 1024);       // f16 cast, 8 MB
  f16* w2iH = (f16*)(tmp + (size_t)12 * 1024 * 1024);      // f16 cast, 8 MB

  {  // weight transposes + f16 casts (grid = (N/32, K/32) for W[K,N])
    dim3 b(32, 8);
    wtr_k<<<dim3(32, 32), b, 0, stream>>>(Wp, WpT, 1024, 1024);
    wtr_k<<<dim3(128, 32), b, 0, stream>>>(w1r, w1rT, 1024, 4096);
    wtr_k<<<dim3(128, 32), b, 0, stream>>>(w1i, w1iT, 1024, 4096);
    wtr_k<<<dim3(64, 32), b, 0, stream>>>(wf1, wf1T, 1024, 2048);
    wtr_k<<<dim3(32, 64), b, 0, stream>>>(wf2, wf2T, 2048, 1024);
    wtr_k<<<dim3(32, 64), b, 0, stream>>>(We, WeT, 2048, 1024);
    cast_k<<<dim3(4096), 256, 0, stream>>>(w2r, w2rH);
    cast_k<<<dim3(4096), 256, 0, stream>>>(w2i, w2iH);
  }

  colsq_k<<<dim3(4, 16, 4), 256, 0, stream>>>(x, part);
  stats_k<<<4, 256, 0, stream>>>(part, GsumB, ampB);
  rowterm_k<<<dim3(4, 4), 256, 0, stream>>>(ampB, Wa, ba, bp, gbias, rowterm);
  bc_k<<<dim3(4), 256, 0, stream>>>(b2r, b2i, We, be, bcB);

  // WcT[n, 0:4096]  = (w2r @ We_top)^T ; WcT[n, 4096:8192] = (w2i @ We_bot)^T
  gemm_k<5><<<dim3(8, 32), 256, 0, stream>>>(WeT, 2048, w2rH, 1024, 1024, nullptr,
      nullptr, WcT, 8192, nullptr, nullptr, nullptr, nullptr, nullptr, 0, 0.f, 0.f);
  gemm_k<5><<<dim3(8, 32), 256, 0, stream>>>(WeT + 1024, 2048, w2iH, 1024, 1024, nullptr,
      nullptr, WcT + 4096, 8192, nullptr, nullptr, nullptr, nullptr, nullptr, 0, 0.f, 0.f);

  // wave_repr collapses: ratio = (x<0 ? -0.99 : 0), sqrt_term = (x<0 ? sqrt(1-.99^2) : 1)
  const float ratioNeg = -0.99f;
  const float stNeg = sqrtf(fmaxf(1.0f - 0.99f * 0.99f, EPSF));
  const float phPos = atan2f(1.0f, 0.0f);
  const float phNeg = atan2f(stNeg, ratioNeg);

  const long Ntok = (long)in_sizes[0] / 1024;  // 16384
  const size_t perRow = 26624;  // ph 2K + gr 2K + gi 2K + h1 16K + wave/h2 4K
  long R = (long)((ws_size > staticEnd ? ws_size - staticEnd : 0) / perRow);
  R &= ~127L;
  if (R > Ntok) R = Ntok;
  if (R < 128) R = 128;

  char* cb = ws + staticEnd;
  f16* phB = (f16*)cb;                               // R x 1024
  f16* grB = (f16*)(cb + (size_t)R * 2048);          // R x 1024
  f16* giB = (f16*)(cb + (size_t)R * 4096);          // R x 1024
  f16* h1B = (f16*)(cb + (size_t)R * 6144);          // R x 8192 (r|i halves)
  char* wvB = cb + (size_t)R * 6144 + (size_t)R * 16384;
  float* waveF = (float*)wvB;                        // R x 1024 f32
  f16* h2B = (f16*)wvB;                              // R x 2048 f16 (after waveF dead)
  f16* outB = phB;                                   // reuse after gate consumed ph

  for (long r0 = 0; r0 < Ntok; r0 += R) {
    const long Rc = (Ntok - r0 < R) ? (Ntok - r0) : R;
    const int gx = (int)(Rc / 128);
    ph_k<<<dim3((int)Rc), 256, 0, stream>>>(x + r0 * 1024, phB, phPos, phNeg);
    // gate: pre = ph@Wp + rowterm; gr/gi = (cr/ci)*sigmoid(pre)
    gemm_k<4><<<dim3(gx, 8), 256, 0, stream>>>(phB, 1024, WpT, 1024, 1024, nullptr,
        nullptr, nullptr, 1024, phB, rowterm, GsumB, grB, giB, (int)r0, ratioNeg, stNeg);
    // up-projections -> gelu -> combined h1 [R x 8192]
    gemm_k<3><<<dim3(gx, 32), 256, 0, stream>>>(grB, 1024, w1rT, 1024, 1024, b1r,
        nullptr, h1B, 8192, nullptr, nullptr, nullptr, nullptr, nullptr, 0, 0.f, 0.f);
    gemm_k<3><<<dim3(gx, 32), 256, 0, stream>>>(giB, 1024, w1iT, 1024, 1024, b1i,
        nullptr, h1B + 4096, 8192, nullptr, nullptr, nullptr, nullptr, nullptr, 0, 0.f, 0.f);
    // fused down-proj + We: wave = h1 @ WcT^T + bc
    gemm_k<0><<<dim3(gx, 8), 256, 0, stream>>>(h1B, 8192, WcT, 8192, 8192, bcB,
        waveF, nullptr, 1024, nullptr, nullptr, nullptr, nullptr, nullptr, 0, 0.f, 0.f);
    rms_k<<<dim3((int)Rc), 256, 0, stream>>>(waveF, grms, outB);
    // block FFN
    gemm_k<3><<<dim3(gx, 16), 256, 0, stream>>>(outB, 1024, wf1T, 1024, 1024, bf1,
        nullptr, h2B, 2048, nullptr, nullptr, nullptr, nullptr, nullptr, 0, 0.f, 0.f);
    gemm_k<0><<<dim3(gx, 8), 256, 0, stream>>>(h2B, 2048, wf2T, 2048, 2048, bf2,
        out + r0 * 1024, nullptr, 1024, nullptr, nullptr, nullptr, nullptr, nullptr, 0, 0.f, 0.f);
  }
}